// Round 8
// baseline (218.482 us; speedup 1.0000x reference)
//
#include <hip/hip_runtime.h>

#define N_NODES 50000
#define N_EDGES 800000
#define D 64

#define NPB 200                      // nodes per bucket
#define NB  250                      // buckets (NPB*NB == N_NODES)
#define CAP 4096                     // record capacity per bucket (mean 3200, 15.8 sigma)
#define BT  512                      // threads for bin (8 waves)
#define EPT 4                        // edges per thread in bin
#define CHUNK_E (BT * EPT)           // 2048 edges per block
#define NCHUNKS ((N_EDGES + CHUNK_E - 1) / CHUNK_E)   // 391
#define CT  1024                     // bucket_csr threads (16 waves)
#define GL_BLOCKS 768                // gather+linear blocks (3072 waves)

typedef unsigned short ushort_t;
typedef unsigned int   uint_t;

// bf16 helpers (RNE down-convert; up-convert is exact)
__device__ __forceinline__ ushort_t f2b(float f) {
    uint_t u = __float_as_uint(f);
    return (ushort_t)((u + 0x7FFFu + ((u >> 16) & 1u)) >> 16);
}
__device__ __forceinline__ float b2f(ushort_t b) {
    return __uint_as_float((uint_t)b << 16);
}
__device__ __forceinline__ float lane_bcast(float v, int l) {
    return __int_as_float(__builtin_amdgcn_readlane(__float_as_int(v), l));
}

// ---------------------------------------------------------------------------
// ws layout (8B-aligned first):
//   edges  : int2[NB*CAP]     (8.19 MB)  bucket-grouped then node-sorted in place
//   offs2  : int2[N_NODES]    (0.4 MB)   per-node (beg,end)
//   h_bf16 : ushort[N*D]      (6.4 MB)
//   cursor : int[NB]          (memset to 0; positions rebased b*CAP + old)
// Binned record: .x=(src<<8)|local_dst, .y=bits(w). Sorted: .x=src, .y=bits(w).
// ---------------------------------------------------------------------------

// ---------------- K1: bin edges by bucket (blocks < NCHUNKS) + h->bf16 (rest) ----
__global__ __launch_bounds__(BT) void bin_h2b_kernel(
    const int* __restrict__ src, const int* __restrict__ dst,
    const float* __restrict__ w, int* __restrict__ cursor,
    int2* __restrict__ bedges,
    const float* __restrict__ h, ushort_t* __restrict__ hb)
{
    if (blockIdx.x >= NCHUNKS) {
        // ---- h2b portion: grid-stride over float4 groups ----
        const int nb = gridDim.x - NCHUNKS;
        for (int i = (blockIdx.x - NCHUNKS) * BT + threadIdx.x;
             i < N_NODES * D / 4; i += nb * BT) {
            const float4 v = ((const float4*)h)[i];
            ushort4 o;
            o.x = f2b(v.x); o.y = f2b(v.y); o.z = f2b(v.z); o.w = f2b(v.w);
            ((ushort4*)hb)[i] = o;
        }
        return;
    }

    __shared__ int lh[NB];
    __shared__ int loff[NB];
    __shared__ int lcur[NB];
    __shared__ int gpos[NB];
    __shared__ int part[256];
    __shared__ int2 stage[CHUNK_E];
    __shared__ unsigned char sbk[CHUNK_E];

    const int t = threadIdx.x;
    for (int i = t; i < NB; i += BT) lh[i] = 0;
    __syncthreads();

    const int base = blockIdx.x * CHUNK_E;
    int   my_b[EPT];
    int   my_p[EPT];
    float my_w[EPT];
#pragma unroll
    for (int k = 0; k < EPT; ++k) {
        const int e = base + k * BT + t;
        if (e < N_EDGES) {
            const int d = dst[e];
            const int b = (unsigned)d / NPB;
            my_b[k] = b;
            my_p[k] = (src[e] << 8) | (d - b * NPB);
            my_w[k] = w[e];
            atomicAdd(&lh[b], 1);
        } else {
            my_b[k] = -1;
        }
    }
    __syncthreads();

    // exclusive scan of NB counts (first 256 threads)
    const int v = (t < NB) ? lh[t] : 0;
    if (t < 256) part[t] = v;
    __syncthreads();
    for (int off = 1; off < 256; off <<= 1) {
        int p = 0;
        if (t < 256 && t >= off) p = part[t - off];
        __syncthreads();
        if (t < 256) part[t] += p;
        __syncthreads();
    }
    if (t < NB) { loff[t] = part[t] - v; lcur[t] = part[t] - v; }
    __syncthreads();

#pragma unroll
    for (int k = 0; k < EPT; ++k) {
        if (my_b[k] >= 0) {
            const int p = atomicAdd(&lcur[my_b[k]], 1);
            stage[p] = make_int2(my_p[k], __float_as_int(my_w[k]));
            sbk[p] = (unsigned char)my_b[k];
        }
    }
    __syncthreads();

    if (t < NB && lh[t] > 0)
        gpos[t] = t * CAP + atomicAdd(&cursor[t], lh[t]);
    __syncthreads();

    const int tot = min(N_EDGES - base, CHUNK_E);
    for (int s = t; s < tot; s += BT) {
        const int b = sbk[s];
        bedges[gpos[b] + (s - loff[b])] = stage[s];
    }
}

// ---------------- K2: per-bucket node-exact CSR (in place) ----------------
__global__ __launch_bounds__(CT) void bucket_csr_kernel(
    const int* __restrict__ cursor, int2* __restrict__ edges,
    int2* __restrict__ offs2)
{
    __shared__ int  lcur[NPB];
    __shared__ int  part[256];
    __shared__ int2 stage[CAP];

    const int b   = blockIdx.x;
    const int t   = threadIdx.x;
    const int gb  = b * CAP;
    const int cnt = min(cursor[b], CAP);

    // per-node histogram
    if (t < NPB) lcur[t] = 0;
    __syncthreads();
    for (int e = t; e < cnt; e += CT)
        atomicAdd(&lcur[edges[gb + e].x & 255], 1);
    __syncthreads();

    // exclusive scan of NPB counts (first 256 threads)
    const int v = (t < NPB) ? lcur[t] : 0;
    if (t < 256) part[t] = v;
    __syncthreads();
    for (int off = 1; off < 256; off <<= 1) {
        int p = 0;
        if (t < 256 && t >= off) p = part[t - off];
        __syncthreads();
        if (t < 256) part[t] += p;
        __syncthreads();
    }
    if (t < NPB) {
        const int ex = part[t] - v;
        lcur[t] = ex;
        offs2[b * NPB + t] = make_int2(gb + ex, gb + ex + v);
    }
    __syncthreads();

    // position via LDS atomics, scatter into LDS stage
    for (int e = t; e < cnt; e += CT) {
        const int2 r = edges[gb + e];
        const int p = atomicAdd(&lcur[r.x & 255], 1);
        stage[p] = make_int2(r.x >> 8, r.y);
    }
    __syncthreads();
    // fully coalesced in-place flush
    for (int s = t; s < cnt; s += CT)
        edges[gb + s] = stage[s];
}

// ---------------- K3: fused gather + linear + relu, one wave per node ----------------
// Weights held bf16-packed (2 per VGPR): 64 regs for both matrices.
__global__ __launch_bounds__(256) void gather_linear_kernel(
    const ushort_t* __restrict__ hb, const int2* __restrict__ edges,
    const int2* __restrict__ offs2,
    const float* __restrict__ Ws, const float* __restrict__ bs,
    const float* __restrict__ Wn, const float* __restrict__ bn,
    float* __restrict__ out)
{
    const int lane   = threadIdx.x & 63;
    const int gwave  = (blockIdx.x * blockDim.x + threadIdx.x) >> 6;
    const int nwaves = (gridDim.x * blockDim.x) >> 6;

    // lane j holds row j of Ws and Wn, bf16-packed pairs (even in lo, odd in hi)
    uint_t Wsp[D / 2], Wnp[D / 2];
#pragma unroll
    for (int k = 0; k < D; k += 4) {
        const float4 a = *(const float4*)&Ws[(size_t)lane * D + k];
        const float4 b = *(const float4*)&Wn[(size_t)lane * D + k];
        Wsp[k / 2]     = (uint_t)f2b(a.x) | ((uint_t)f2b(a.y) << 16);
        Wsp[k / 2 + 1] = (uint_t)f2b(a.z) | ((uint_t)f2b(a.w) << 16);
        Wnp[k / 2]     = (uint_t)f2b(b.x) | ((uint_t)f2b(b.y) << 16);
        Wnp[k / 2 + 1] = (uint_t)f2b(b.z) | ((uint_t)f2b(b.w) << 16);
    }
    const float bias = bs[lane] + bn[lane];

    for (int n = gwave; n < N_NODES; n += nwaves) {
        const int2 be = offs2[n];
        const int beg = be.x, end = be.y;

        // ---- gather: acc = neigh[n][lane] ----
        float acc = 0.f;
        int e = beg;
        for (; e + 8 <= end; e += 8) {
            int2  r[8];
            float vv[8];
#pragma unroll
            for (int k = 0; k < 8; ++k) r[k] = edges[e + k];
#pragma unroll
            for (int k = 0; k < 8; ++k) vv[k] = b2f(hb[(size_t)r[k].x * D + lane]);
#pragma unroll
            for (int k = 0; k < 8; ++k) acc = fmaf(__int_as_float(r[k].y), vv[k], acc);
        }
        for (; e + 4 <= end; e += 4) {
            const int2 e0 = edges[e], e1 = edges[e + 1], e2 = edges[e + 2], e3 = edges[e + 3];
            const float v0 = b2f(hb[(size_t)e0.x * D + lane]);
            const float v1 = b2f(hb[(size_t)e1.x * D + lane]);
            const float v2 = b2f(hb[(size_t)e2.x * D + lane]);
            const float v3 = b2f(hb[(size_t)e3.x * D + lane]);
            acc = fmaf(__int_as_float(e0.y), v0, acc);
            acc = fmaf(__int_as_float(e1.y), v1, acc);
            acc = fmaf(__int_as_float(e2.y), v2, acc);
            acc = fmaf(__int_as_float(e3.y), v3, acc);
        }
        for (; e < end; ++e) {
            const int2 ed = edges[e];
            acc = fmaf(__int_as_float(ed.y), b2f(hb[(size_t)ed.x * D + lane]), acc);
        }

        // ---- linear: out[n][lane] = relu(sum_k h[n][k]*Ws[lane][k] + acc[k]*Wn[lane][k] + bias)
        const float hv = b2f(hb[(size_t)n * D + lane]);
        float o = bias;
#pragma unroll
        for (int i = 0; i < D / 2; ++i) {
            const float h0 = lane_bcast(hv, 2 * i);
            const float h1 = lane_bcast(hv, 2 * i + 1);
            const float n0 = lane_bcast(acc, 2 * i);
            const float n1 = lane_bcast(acc, 2 * i + 1);
            o = fmaf(h0, __uint_as_float(Wsp[i] << 16), o);
            o = fmaf(h1, __uint_as_float(Wsp[i] & 0xFFFF0000u), o);
            o = fmaf(n0, __uint_as_float(Wnp[i] << 16), o);
            o = fmaf(n1, __uint_as_float(Wnp[i] & 0xFFFF0000u), o);
        }
        out[(size_t)n * D + lane] = fmaxf(o, 0.f);
    }
}

// ---------------- fallback path (ws too small): fp32 atomic scatter ----------------
__global__ __launch_bounds__(256) void sage_scatter(
    const float* __restrict__ h,
    const int* __restrict__ edge_src,
    const int* __restrict__ edge_dst,
    const float* __restrict__ edge_w,
    float* __restrict__ neigh)
{
    const long long tid = (long long)blockIdx.x * blockDim.x + threadIdx.x;
    const int e = (int)(tid >> 6);
    const int d = (int)(tid & 63);
    if (e >= N_EDGES) return;
    atomicAdd(&neigh[(long long)edge_dst[e] * D + d],
              edge_w[e] * h[(long long)edge_src[e] * D + d]);
}

__global__ __launch_bounds__(256, 2) void linear_f32_kernel(
    const float* __restrict__ h, const float* __restrict__ neigh,
    const float* __restrict__ Ws, const float* __restrict__ bs,
    const float* __restrict__ Wn, const float* __restrict__ bn,
    float* __restrict__ out)
{
    const int lane   = threadIdx.x & 63;
    const int gwave  = (blockIdx.x * blockDim.x + threadIdx.x) >> 6;
    const int nwaves = (gridDim.x * blockDim.x) >> 6;

    float Wsr[D], Wnr[D];
#pragma unroll
    for (int k = 0; k < D; k += 4) {
        const float4 a = *(const float4*)&Ws[(size_t)lane * D + k];
        const float4 b = *(const float4*)&Wn[(size_t)lane * D + k];
        Wsr[k] = a.x; Wsr[k+1] = a.y; Wsr[k+2] = a.z; Wsr[k+3] = a.w;
        Wnr[k] = b.x; Wnr[k+1] = b.y; Wnr[k+2] = b.z; Wnr[k+3] = b.w;
    }
    const float bias = bs[lane] + bn[lane];

    for (int n = gwave; n < N_NODES; n += nwaves) {
        const float hv = h[(size_t)n * D + lane];
        const float nv = neigh[(size_t)n * D + lane];
        float o = bias;
#pragma unroll
        for (int k = 0; k < D; ++k) {
            o = fmaf(lane_bcast(hv, k), Wsr[k], o);
            o = fmaf(lane_bcast(nv, k), Wnr[k], o);
        }
        out[(size_t)n * D + lane] = fmaxf(o, 0.f);
    }
}

extern "C" void kernel_launch(void* const* d_in, const int* in_sizes, int n_in,
                              void* d_out, int out_size, void* d_ws, size_t ws_size,
                              hipStream_t stream)
{
    const float* h        = (const float*)d_in[0];
    const int*   edge_src = (const int*)d_in[1];
    const int*   edge_dst = (const int*)d_in[2];
    const float* edge_w   = (const float*)d_in[3];
    const float* W_self   = (const float*)d_in[4];
    const float* b_self   = (const float*)d_in[5];
    const float* W_neigh  = (const float*)d_in[6];
    const float* b_neigh  = (const float*)d_in[7];
    float*       out      = (float*)d_out;

    // ws layout
    int2*     edges  = (int2*)d_ws;                               // NB*CAP int2
    int2*     offs2  = edges + (size_t)NB * CAP;                  // N_NODES int2
    ushort_t* hb     = (ushort_t*)(offs2 + N_NODES);              // N*D ushort
    int*      cursor = (int*)(hb + (size_t)N_NODES * D);          // NB
    const size_t needed = (size_t)NB * CAP * 8 + (size_t)N_NODES * 8
                        + (size_t)N_NODES * D * 2 + NB * 4;

    if (ws_size >= needed) {
        hipMemsetAsync(cursor, 0, NB * sizeof(int), stream);
        bin_h2b_kernel<<<NCHUNKS * 2, BT, 0, stream>>>(
            edge_src, edge_dst, edge_w, cursor, edges, h, hb);
        bucket_csr_kernel<<<NB, CT, 0, stream>>>(cursor, edges, offs2);
        gather_linear_kernel<<<GL_BLOCKS, 256, 0, stream>>>(
            hb, edges, offs2, W_self, b_self, W_neigh, b_neigh, out);
    } else {
        float* neigh_fb = (float*)d_ws;
        hipMemsetAsync(neigh_fb, 0, (size_t)N_NODES * D * sizeof(float), stream);
        const long long total = (long long)N_EDGES * 64;
        sage_scatter<<<(int)((total + 255) / 256), 256, 0, stream>>>(
            h, edge_src, edge_dst, edge_w, neigh_fb);
        linear_f32_kernel<<<1024, 256, 0, stream>>>(h, neigh_fb, W_self, b_self,
                                                    W_neigh, b_neigh, out);
    }
}

// Round 9
// 167.991 us; speedup vs baseline: 1.3006x; 1.3006x over previous
//
#include <hip/hip_runtime.h>

#define N_NODES 50000
#define N_EDGES 800000
#define D 64

#define NPB 200                      // nodes per bucket
#define NB  250                      // buckets (NPB*NB == N_NODES)
#define CAP 4096                     // record capacity per bucket (mean 3200, 15.8 sigma)
#define BT  512                      // threads for bin (8 waves)
#define EPT 4                        // edges per thread in bin
#define CHUNK_E (BT * EPT)           // 2048 edges per block
#define NCHUNKS ((N_EDGES + CHUNK_E - 1) / CHUNK_E)   // 391
#define NSEG 4                       // csr sub-segments per bucket
#define SEG_MAX (CAP / NSEG)         // 1024 records per csr block

typedef unsigned short ushort_t;
typedef unsigned int   uint_t;
typedef __attribute__((ext_vector_type(8))) short   short8;
typedef __attribute__((ext_vector_type(4))) float   float4v;

// bf16 helpers (RNE down-convert; up-convert is exact)
__device__ __forceinline__ ushort_t f2b(float f) {
    uint_t u = __float_as_uint(f);
    return (ushort_t)((u + 0x7FFFu + ((u >> 16) & 1u)) >> 16);
}
__device__ __forceinline__ float b2f(ushort_t b) {
    return __uint_as_float((uint_t)b << 16);
}
__device__ __forceinline__ float lane_bcast(float v, int l) {
    return __int_as_float(__builtin_amdgcn_readlane(__float_as_int(v), l));
}

// ---------------------------------------------------------------------------
// ws layout (16B-aligned sections):
//   edges  : int2[NB*CAP]        (8.19 MB) bucket-grouped then node-sorted in place
//   offs2  : int2[NSEG*N_NODES]  (1.6 MB)  per-(segment,node) (beg,end)
//   h_bf16 : ushort[N*D]         (6.4 MB)
//   neighb : ushort[N*D]         (6.4 MB)
//   cursor : int[NB]             (memset 0; bin rebases to b*CAP + old)
// Binned record: .x=(src<<8)|local_dst, .y=bits(w). Sorted: .x=src, .y=bits(w).
// ---------------------------------------------------------------------------

// ---------------- K1: bin edges by bucket (blocks < NCHUNKS) + h->bf16 (rest) ----
__global__ __launch_bounds__(BT) void bin_h2b_kernel(
    const int* __restrict__ src, const int* __restrict__ dst,
    const float* __restrict__ w, int* __restrict__ cursor,
    int2* __restrict__ bedges,
    const float* __restrict__ h, ushort_t* __restrict__ hb)
{
    if (blockIdx.x >= NCHUNKS) {
        const int nb = gridDim.x - NCHUNKS;
        for (int i = (blockIdx.x - NCHUNKS) * BT + threadIdx.x;
             i < N_NODES * D / 4; i += nb * BT) {
            const float4 v = ((const float4*)h)[i];
            ushort4 o;
            o.x = f2b(v.x); o.y = f2b(v.y); o.z = f2b(v.z); o.w = f2b(v.w);
            ((ushort4*)hb)[i] = o;
        }
        return;
    }

    __shared__ int lh[NB];
    __shared__ int loff[NB];
    __shared__ int lcur[NB];
    __shared__ int gpos[NB];
    __shared__ int part[256];
    __shared__ int2 stage[CHUNK_E];
    __shared__ unsigned char sbk[CHUNK_E];

    const int t = threadIdx.x;
    for (int i = t; i < NB; i += BT) lh[i] = 0;
    __syncthreads();

    const int base = blockIdx.x * CHUNK_E;
    int   my_b[EPT];
    int   my_p[EPT];
    float my_w[EPT];
#pragma unroll
    for (int k = 0; k < EPT; ++k) {
        const int e = base + k * BT + t;
        if (e < N_EDGES) {
            const int d = dst[e];
            const int b = (unsigned)d / NPB;
            my_b[k] = b;
            my_p[k] = (src[e] << 8) | (d - b * NPB);
            my_w[k] = w[e];
            atomicAdd(&lh[b], 1);
        } else {
            my_b[k] = -1;
        }
    }
    __syncthreads();

    const int v = (t < NB) ? lh[t] : 0;
    if (t < 256) part[t] = v;
    __syncthreads();
    for (int off = 1; off < 256; off <<= 1) {
        int p = 0;
        if (t < 256 && t >= off) p = part[t - off];
        __syncthreads();
        if (t < 256) part[t] += p;
        __syncthreads();
    }
    if (t < NB) { loff[t] = part[t] - v; lcur[t] = part[t] - v; }
    __syncthreads();

#pragma unroll
    for (int k = 0; k < EPT; ++k) {
        if (my_b[k] >= 0) {
            const int p = atomicAdd(&lcur[my_b[k]], 1);
            stage[p] = make_int2(my_p[k], __float_as_int(my_w[k]));
            sbk[p] = (unsigned char)my_b[k];
        }
    }
    __syncthreads();

    if (t < NB && lh[t] > 0)
        gpos[t] = t * CAP + atomicAdd(&cursor[t], lh[t]);
    __syncthreads();

    const int tot = min(N_EDGES - base, CHUNK_E);
    for (int s = t; s < tot; s += BT) {
        const int b = sbk[s];
        bedges[gpos[b] + (s - loff[b])] = stage[s];
    }
}

// ---------------- K2: per-(bucket,quarter) node-exact sort (in place) ----------------
__global__ __launch_bounds__(256) void bucket_csr4_kernel(
    const int* __restrict__ cursor, int2* __restrict__ edges,
    int2* __restrict__ offs2)
{
    __shared__ int  lcur[NPB];
    __shared__ int  part[256];
    __shared__ int2 stage[SEG_MAX];

    const int b   = blockIdx.x >> 2;
    const int s   = blockIdx.x & 3;
    const int t   = threadIdx.x;
    const int cnt = min(cursor[b], CAP);
    const int lo  = (cnt * s) >> 2;
    const int hi  = (cnt * (s + 1)) >> 2;
    const int n   = hi - lo;
    const int gb  = b * CAP + lo;

    // per-node histogram of this quarter
    if (t < NPB) lcur[t] = 0;
    __syncthreads();
    for (int e = t; e < n; e += 256)
        atomicAdd(&lcur[edges[gb + e].x & 255], 1);
    __syncthreads();

    // exclusive scan of NPB counts
    const int v = (t < NPB) ? lcur[t] : 0;
    part[t] = v;
    __syncthreads();
    for (int off = 1; off < 256; off <<= 1) {
        int p = (t >= off) ? part[t - off] : 0;
        __syncthreads();
        part[t] += p;
        __syncthreads();
    }
    if (t < NPB) {
        const int ex = part[t] - v;
        lcur[t] = ex;
        offs2[s * N_NODES + b * NPB + t] = make_int2(gb + ex, gb + ex + v);
    }
    __syncthreads();

    // position via LDS atomics, scatter into LDS stage
    for (int e = t; e < n; e += 256) {
        const int2 r = edges[gb + e];
        const int p = atomicAdd(&lcur[r.x & 255], 1);
        stage[p] = make_int2(r.x >> 8, r.y);
    }
    __syncthreads();
    // coalesced in-place flush
    for (int e = t; e < n; e += 256)
        edges[gb + e] = stage[e];
}

// ---------------- K3: gather, one wave per node, flattened 4-segment stream ----------
__global__ __launch_bounds__(256) void gather_kernel(
    const ushort_t* __restrict__ hb, const int2* __restrict__ edges,
    const int2* __restrict__ offs2, ushort_t* __restrict__ neigh)
{
    const int node = (blockIdx.x * 256 + threadIdx.x) >> 6;
    const int lane = threadIdx.x & 63;
    if (node >= N_NODES) return;

    int sb[NSEG], se[NSEG];
    int total = 0;
#pragma unroll
    for (int s = 0; s < NSEG; ++s) {
        const int2 p = offs2[s * N_NODES + node];
        sb[s] = p.x; se[s] = p.y;
        total += p.y - p.x;
    }

    int s = 0, cur = sb[0];
    float acc = 0.f;
    int i = 0;
    for (; i + 8 <= total; i += 8) {
        int idx[8];
#pragma unroll
        for (int k = 0; k < 8; ++k) {
            while (s < NSEG - 1 && cur >= se[s]) { ++s; cur = sb[s]; }
            idx[k] = cur++;
        }
        int2  r[8];
        float vv[8];
#pragma unroll
        for (int k = 0; k < 8; ++k) r[k] = edges[idx[k]];
#pragma unroll
        for (int k = 0; k < 8; ++k) vv[k] = b2f(hb[(size_t)r[k].x * D + lane]);
#pragma unroll
        for (int k = 0; k < 8; ++k) acc = fmaf(__int_as_float(r[k].y), vv[k], acc);
    }
    for (; i < total; ++i) {
        while (s < NSEG - 1 && cur >= se[s]) { ++s; cur = sb[s]; }
        const int2 r = edges[cur++];
        acc = fmaf(__int_as_float(r.y), b2f(hb[(size_t)r.x * D + lane]), acc);
    }
    neigh[(size_t)node * D + lane] = f2b(acc);
}

// ---------------- K4: MFMA linear: out = relu(h@Ws^T + neigh@Wn^T + bias) --------
// Wave = 16 nodes x 64 outputs. A/B frags: row = lane&15, 8 consecutive K at
// (lane>>4)*8 (+kt*32). C/D: col=lane&15, row=(lane>>4)*4+reg  [m89-verified].
__global__ __launch_bounds__(256) void linear_mfma_kernel(
    const ushort_t* __restrict__ hb, const ushort_t* __restrict__ nb,
    const float* __restrict__ Ws, const float* __restrict__ bs,
    const float* __restrict__ Wn, const float* __restrict__ bn,
    float* __restrict__ out)
{
    const int wave  = (blockIdx.x * 256 + threadIdx.x) >> 6;
    const int node0 = wave * 16;
    if (node0 >= N_NODES) return;
    const int lane  = threadIdx.x & 63;
    const int row16 = lane & 15;
    const int quad  = lane >> 4;

    // A fragments: X rows (h and neigh), 2 K-tiles each
    const size_t abase = (size_t)(node0 + row16) * D + quad * 8;
    const short8 ah0 = *(const short8*)(hb + abase);
    const short8 ah1 = *(const short8*)(hb + abase + 32);
    const short8 an0 = *(const short8*)(nb + abase);
    const short8 an1 = *(const short8*)(nb + abase + 32);

#pragma unroll
    for (int nt = 0; nt < 4; ++nt) {
        const int col = nt * 16 + row16;
        // B fragments: W rows (already "B^T layout": row = output, K contiguous)
        const float* wsr = Ws + (size_t)col * D + quad * 8;
        const float* wnr = Wn + (size_t)col * D + quad * 8;
        short8 bw[4];   // ws_k0, ws_k1, wn_k0, wn_k1
#pragma unroll
        for (int f = 0; f < 4; ++f) {
            const float* p = (f < 2 ? wsr : wnr) + (f & 1) * 32;
            const float4 w0 = *(const float4*)p;
            const float4 w1 = *(const float4*)(p + 4);
            short8 bwv;
            bwv[0] = (short)f2b(w0.x); bwv[1] = (short)f2b(w0.y);
            bwv[2] = (short)f2b(w0.z); bwv[3] = (short)f2b(w0.w);
            bwv[4] = (short)f2b(w1.x); bwv[5] = (short)f2b(w1.y);
            bwv[6] = (short)f2b(w1.z); bwv[7] = (short)f2b(w1.w);
            bw[f] = bwv;
        }
        float4v acc = {0.f, 0.f, 0.f, 0.f};
        acc = __builtin_amdgcn_mfma_f32_16x16x32_bf16(ah0, bw[0], acc, 0, 0, 0);
        acc = __builtin_amdgcn_mfma_f32_16x16x32_bf16(ah1, bw[1], acc, 0, 0, 0);
        acc = __builtin_amdgcn_mfma_f32_16x16x32_bf16(an0, bw[2], acc, 0, 0, 0);
        acc = __builtin_amdgcn_mfma_f32_16x16x32_bf16(an1, bw[3], acc, 0, 0, 0);

        const float bias = bs[col] + bn[col];
#pragma unroll
        for (int r = 0; r < 4; ++r) {
            const int m = quad * 4 + r;
            out[(size_t)(node0 + m) * D + col] = fmaxf(acc[r] + bias, 0.f);
        }
    }
}

// ---------------- fallback path (ws too small): fp32 atomic scatter ----------------
__global__ __launch_bounds__(256) void sage_scatter(
    const float* __restrict__ h,
    const int* __restrict__ edge_src,
    const int* __restrict__ edge_dst,
    const float* __restrict__ edge_w,
    float* __restrict__ neigh)
{
    const long long tid = (long long)blockIdx.x * blockDim.x + threadIdx.x;
    const int e = (int)(tid >> 6);
    const int d = (int)(tid & 63);
    if (e >= N_EDGES) return;
    atomicAdd(&neigh[(long long)edge_dst[e] * D + d],
              edge_w[e] * h[(long long)edge_src[e] * D + d]);
}

__global__ __launch_bounds__(256, 2) void linear_f32_kernel(
    const float* __restrict__ h, const float* __restrict__ neigh,
    const float* __restrict__ Ws, const float* __restrict__ bs,
    const float* __restrict__ Wn, const float* __restrict__ bn,
    float* __restrict__ out)
{
    const int lane   = threadIdx.x & 63;
    const int gwave  = (blockIdx.x * blockDim.x + threadIdx.x) >> 6;
    const int nwaves = (gridDim.x * blockDim.x) >> 6;

    float Wsr[D], Wnr[D];
#pragma unroll
    for (int k = 0; k < D; k += 4) {
        const float4 a = *(const float4*)&Ws[(size_t)lane * D + k];
        const float4 b = *(const float4*)&Wn[(size_t)lane * D + k];
        Wsr[k] = a.x; Wsr[k+1] = a.y; Wsr[k+2] = a.z; Wsr[k+3] = a.w;
        Wnr[k] = b.x; Wnr[k+1] = b.y; Wnr[k+2] = b.z; Wnr[k+3] = b.w;
    }
    const float bias = bs[lane] + bn[lane];

    for (int n = gwave; n < N_NODES; n += nwaves) {
        const float hv = h[(size_t)n * D + lane];
        const float nv = neigh[(size_t)n * D + lane];
        float o = bias;
#pragma unroll
        for (int k = 0; k < D; ++k) {
            o = fmaf(lane_bcast(hv, k), Wsr[k], o);
            o = fmaf(lane_bcast(nv, k), Wnr[k], o);
        }
        out[(size_t)n * D + lane] = fmaxf(o, 0.f);
    }
}

extern "C" void kernel_launch(void* const* d_in, const int* in_sizes, int n_in,
                              void* d_out, int out_size, void* d_ws, size_t ws_size,
                              hipStream_t stream)
{
    const float* h        = (const float*)d_in[0];
    const int*   edge_src = (const int*)d_in[1];
    const int*   edge_dst = (const int*)d_in[2];
    const float* edge_w   = (const float*)d_in[3];
    const float* W_self   = (const float*)d_in[4];
    const float* b_self   = (const float*)d_in[5];
    const float* W_neigh  = (const float*)d_in[6];
    const float* b_neigh  = (const float*)d_in[7];
    float*       out      = (float*)d_out;

    // ws layout
    int2*     edges  = (int2*)d_ws;                               // NB*CAP int2
    int2*     offs2  = edges + (size_t)NB * CAP;                  // NSEG*N_NODES int2
    ushort_t* hb     = (ushort_t*)(offs2 + (size_t)NSEG * N_NODES);
    ushort_t* neighb = hb + (size_t)N_NODES * D;
    int*      cursor = (int*)(neighb + (size_t)N_NODES * D);      // NB
    const size_t needed = (size_t)NB * CAP * 8 + (size_t)NSEG * N_NODES * 8
                        + (size_t)N_NODES * D * 2 * 2 + NB * 4;

    if (ws_size >= needed) {
        hipMemsetAsync(cursor, 0, NB * sizeof(int), stream);
        bin_h2b_kernel<<<NCHUNKS * 2, BT, 0, stream>>>(
            edge_src, edge_dst, edge_w, cursor, edges, h, hb);
        bucket_csr4_kernel<<<NB * NSEG, 256, 0, stream>>>(cursor, edges, offs2);
        gather_kernel<<<(N_NODES * 64 + 255) / 256, 256, 0, stream>>>(
            hb, edges, offs2, neighb);
        linear_mfma_kernel<<<(N_NODES / 16 + 3) / 4, 256, 0, stream>>>(
            hb, neighb, W_self, b_self, W_neigh, b_neigh, out);
    } else {
        float* neigh_fb = (float*)d_ws;
        hipMemsetAsync(neigh_fb, 0, (size_t)N_NODES * D * sizeof(float), stream);
        const long long total = (long long)N_EDGES * 64;
        sage_scatter<<<(int)((total + 255) / 256), 256, 0, stream>>>(
            h, edge_src, edge_dst, edge_w, neigh_fb);
        linear_f32_kernel<<<1024, 256, 0, stream>>>(h, neigh_fb, W_self, b_self,
                                                    W_neigh, b_neigh, out);
    }
}

// Round 10
// 165.975 us; speedup vs baseline: 1.3164x; 1.0121x over previous
//
#include <hip/hip_runtime.h>

#define N_NODES 50000
#define N_EDGES 800000
#define D 64

#define NPB 200                      // nodes per bucket
#define NB  250                      // buckets (NPB*NB == N_NODES)
#define CAP 4096                     // record capacity per bucket (mean 3200, 15.8 sigma)
#define BT  512                      // threads for bin (8 waves)
#define EPT 4                        // edges per thread in bin
#define CHUNK_E (BT * EPT)           // 2048 edges per block
#define NCHUNKS ((N_EDGES + CHUNK_E - 1) / CHUNK_E)   // 391
#define CT  1024                     // bucket_csr threads (16 waves)
#define GBLK 64                      // nodes per fused gather+linear block

typedef unsigned short ushort_t;
typedef unsigned int   uint_t;
typedef __attribute__((ext_vector_type(8))) short   short8;
typedef __attribute__((ext_vector_type(4))) float   float4v;

// bf16 helpers (RNE down-convert; up-convert is exact)
__device__ __forceinline__ ushort_t f2b(float f) {
    uint_t u = __float_as_uint(f);
    return (ushort_t)((u + 0x7FFFu + ((u >> 16) & 1u)) >> 16);
}
__device__ __forceinline__ float b2f(ushort_t b) {
    return __uint_as_float((uint_t)b << 16);
}
__device__ __forceinline__ float lane_bcast(float v, int l) {
    return __int_as_float(__builtin_amdgcn_readlane(__float_as_int(v), l));
}

// ---------------------------------------------------------------------------
// ws layout (16B-aligned sections):
//   edges  : int2[NB*CAP]     (8.19 MB) bucket-grouped then node-sorted in place
//   offs2  : int2[N_NODES]    (0.4 MB)  per-node (beg,end)
//   h_bf16 : ushort[N*D]      (6.4 MB)
//   cursor : int[NB]          (memset 0; bin rebases to b*CAP + old)
// Binned record: .x=(src<<8)|local_dst, .y=bits(w). Sorted: .x=src, .y=bits(w).
// neigh never touches global: staged in LDS inside the fused kernel.
// ---------------------------------------------------------------------------

// ---------------- K1: bin edges by bucket (blocks < NCHUNKS) + h->bf16 (rest) ----
__global__ __launch_bounds__(BT) void bin_h2b_kernel(
    const int* __restrict__ src, const int* __restrict__ dst,
    const float* __restrict__ w, int* __restrict__ cursor,
    int2* __restrict__ bedges,
    const float* __restrict__ h, ushort_t* __restrict__ hb)
{
    if (blockIdx.x >= NCHUNKS) {
        const int nb = gridDim.x - NCHUNKS;
        for (int i = (blockIdx.x - NCHUNKS) * BT + threadIdx.x;
             i < N_NODES * D / 4; i += nb * BT) {
            const float4 v = ((const float4*)h)[i];
            ushort4 o;
            o.x = f2b(v.x); o.y = f2b(v.y); o.z = f2b(v.z); o.w = f2b(v.w);
            ((ushort4*)hb)[i] = o;
        }
        return;
    }

    __shared__ int lh[NB];
    __shared__ int loff[NB];
    __shared__ int lcur[NB];
    __shared__ int gpos[NB];
    __shared__ int part[256];
    __shared__ int2 stage[CHUNK_E];
    __shared__ unsigned char sbk[CHUNK_E];

    const int t = threadIdx.x;
    for (int i = t; i < NB; i += BT) lh[i] = 0;
    __syncthreads();

    const int base = blockIdx.x * CHUNK_E;
    int   my_b[EPT];
    int   my_p[EPT];
    float my_w[EPT];
#pragma unroll
    for (int k = 0; k < EPT; ++k) {
        const int e = base + k * BT + t;
        if (e < N_EDGES) {
            const int d = dst[e];
            const int b = (unsigned)d / NPB;
            my_b[k] = b;
            my_p[k] = (src[e] << 8) | (d - b * NPB);
            my_w[k] = w[e];
            atomicAdd(&lh[b], 1);
        } else {
            my_b[k] = -1;
        }
    }
    __syncthreads();

    const int v = (t < NB) ? lh[t] : 0;
    if (t < 256) part[t] = v;
    __syncthreads();
    for (int off = 1; off < 256; off <<= 1) {
        int p = 0;
        if (t < 256 && t >= off) p = part[t - off];
        __syncthreads();
        if (t < 256) part[t] += p;
        __syncthreads();
    }
    if (t < NB) { loff[t] = part[t] - v; lcur[t] = part[t] - v; }
    __syncthreads();

#pragma unroll
    for (int k = 0; k < EPT; ++k) {
        if (my_b[k] >= 0) {
            const int p = atomicAdd(&lcur[my_b[k]], 1);
            stage[p] = make_int2(my_p[k], __float_as_int(my_w[k]));
            sbk[p] = (unsigned char)my_b[k];
        }
    }
    __syncthreads();

    if (t < NB && lh[t] > 0)
        gpos[t] = t * CAP + atomicAdd(&cursor[t], lh[t]);
    __syncthreads();

    const int tot = min(N_EDGES - base, CHUNK_E);
    for (int s = t; s < tot; s += BT) {
        const int b = sbk[s];
        bedges[gpos[b] + (s - loff[b])] = stage[s];
    }
}

// ---------------- K2: per-bucket node-exact CSR (in place) ----------------
__global__ __launch_bounds__(CT) void bucket_csr_kernel(
    const int* __restrict__ cursor, int2* __restrict__ edges,
    int2* __restrict__ offs2)
{
    __shared__ int  lcur[NPB];
    __shared__ int  part[256];
    __shared__ int2 stage[CAP];

    const int b   = blockIdx.x;
    const int t   = threadIdx.x;
    const int gb  = b * CAP;
    const int cnt = min(cursor[b], CAP);

    // per-node histogram
    if (t < NPB) lcur[t] = 0;
    __syncthreads();
    for (int e = t; e < cnt; e += CT)
        atomicAdd(&lcur[edges[gb + e].x & 255], 1);
    __syncthreads();

    // exclusive scan of NPB counts (first 256 threads)
    const int v = (t < NPB) ? lcur[t] : 0;
    if (t < 256) part[t] = v;
    __syncthreads();
    for (int off = 1; off < 256; off <<= 1) {
        int p = 0;
        if (t < 256 && t >= off) p = part[t - off];
        __syncthreads();
        if (t < 256) part[t] += p;
        __syncthreads();
    }
    if (t < NPB) {
        const int ex = part[t] - v;
        lcur[t] = ex;
        offs2[b * NPB + t] = make_int2(gb + ex, gb + ex + v);
    }
    __syncthreads();

    // position via LDS atomics, scatter into LDS stage
    for (int e = t; e < cnt; e += CT) {
        const int2 r = edges[gb + e];
        const int p = atomicAdd(&lcur[r.x & 255], 1);
        stage[p] = make_int2(r.x >> 8, r.y);
    }
    __syncthreads();
    // fully coalesced in-place flush
    for (int s = t; s < cnt; s += CT)
        edges[gb + s] = stage[s];
}

// ---------------- K3: fused gather (phase 1, per-wave) + MFMA linear (phase 2) ----
// Block = 64 nodes. Phase 1: wave w gathers nodes [w*16, w*16+16), 8-deep MLP,
// results to LDS (bf16). Phase 2: wave w runs the 16x16x32 MFMA tile for its
// 16 nodes (neigh A-frags from LDS, h from global).  No intra-wave serial
// dependency between a node's loads and long VALU chains (R8 failure mode).
__global__ __launch_bounds__(256) void gather_linear_kernel(
    const ushort_t* __restrict__ hb, const int2* __restrict__ edges,
    const int2* __restrict__ offs2,
    const float* __restrict__ Ws, const float* __restrict__ bs,
    const float* __restrict__ Wn, const float* __restrict__ bn,
    float* __restrict__ out)
{
    __shared__ ushort_t nstage[GBLK * D];   // 8 KB

    const int wave  = threadIdx.x >> 6;
    const int lane  = threadIdx.x & 63;
    const int nbase = blockIdx.x * GBLK + wave * 16;

    // ---- phase 1: gather 16 nodes per wave ----
    for (int j = 0; j < 16; ++j) {
        const int node = nbase + j;
        if (node >= N_NODES) break;
        const int2 be = offs2[node];
        const int beg = be.x, end = be.y;
        float acc = 0.f;
        int e = beg;
        for (; e + 8 <= end; e += 8) {
            int2  r[8];
            float vv[8];
#pragma unroll
            for (int k = 0; k < 8; ++k) r[k] = edges[e + k];
#pragma unroll
            for (int k = 0; k < 8; ++k) vv[k] = b2f(hb[(size_t)r[k].x * D + lane]);
#pragma unroll
            for (int k = 0; k < 8; ++k) acc = fmaf(__int_as_float(r[k].y), vv[k], acc);
        }
        for (; e + 4 <= end; e += 4) {
            const int2 e0 = edges[e], e1 = edges[e + 1], e2 = edges[e + 2], e3 = edges[e + 3];
            const float v0 = b2f(hb[(size_t)e0.x * D + lane]);
            const float v1 = b2f(hb[(size_t)e1.x * D + lane]);
            const float v2 = b2f(hb[(size_t)e2.x * D + lane]);
            const float v3 = b2f(hb[(size_t)e3.x * D + lane]);
            acc = fmaf(__int_as_float(e0.y), v0, acc);
            acc = fmaf(__int_as_float(e1.y), v1, acc);
            acc = fmaf(__int_as_float(e2.y), v2, acc);
            acc = fmaf(__int_as_float(e3.y), v3, acc);
        }
        for (; e < end; ++e) {
            const int2 r = edges[e];
            acc = fmaf(__int_as_float(r.y), b2f(hb[(size_t)r.x * D + lane]), acc);
        }
        nstage[(wave * 16 + j) * D + lane] = f2b(acc);
    }
    __syncthreads();

    // ---- phase 2: MFMA tile (16 nodes x 64 outputs) per wave ----
    const int node0 = nbase;
    if (node0 >= N_NODES) return;
    const int row16 = lane & 15;
    const int quad  = lane >> 4;

    const size_t abase = (size_t)(node0 + row16) * D + quad * 8;
    const short8 ah0 = *(const short8*)(hb + abase);
    const short8 ah1 = *(const short8*)(hb + abase + 32);
    const ushort_t* sp = nstage + (wave * 16 + row16) * D + quad * 8;
    const short8 an0 = *(const short8*)sp;
    const short8 an1 = *(const short8*)(sp + 32);

#pragma unroll
    for (int nt = 0; nt < 4; ++nt) {
        const int col = nt * 16 + row16;
        const float* wsr = Ws + (size_t)col * D + quad * 8;
        const float* wnr = Wn + (size_t)col * D + quad * 8;
        short8 bw[4];   // ws_k0, ws_k1, wn_k0, wn_k1
#pragma unroll
        for (int f = 0; f < 4; ++f) {
            const float* p = (f < 2 ? wsr : wnr) + (f & 1) * 32;
            const float4 w0 = *(const float4*)p;
            const float4 w1 = *(const float4*)(p + 4);
            short8 bwv;
            bwv[0] = (short)f2b(w0.x); bwv[1] = (short)f2b(w0.y);
            bwv[2] = (short)f2b(w0.z); bwv[3] = (short)f2b(w0.w);
            bwv[4] = (short)f2b(w1.x); bwv[5] = (short)f2b(w1.y);
            bwv[6] = (short)f2b(w1.z); bwv[7] = (short)f2b(w1.w);
            bw[f] = bwv;
        }
        float4v acc = {0.f, 0.f, 0.f, 0.f};
        acc = __builtin_amdgcn_mfma_f32_16x16x32_bf16(ah0, bw[0], acc, 0, 0, 0);
        acc = __builtin_amdgcn_mfma_f32_16x16x32_bf16(ah1, bw[1], acc, 0, 0, 0);
        acc = __builtin_amdgcn_mfma_f32_16x16x32_bf16(an0, bw[2], acc, 0, 0, 0);
        acc = __builtin_amdgcn_mfma_f32_16x16x32_bf16(an1, bw[3], acc, 0, 0, 0);

        const float bias = bs[col] + bn[col];
#pragma unroll
        for (int r = 0; r < 4; ++r) {
            const int m = quad * 4 + r;
            out[(size_t)(node0 + m) * D + col] = fmaxf(acc[r] + bias, 0.f);
        }
    }
}

// ---------------- fallback path (ws too small): fp32 atomic scatter ----------------
__global__ __launch_bounds__(256) void sage_scatter(
    const float* __restrict__ h,
    const int* __restrict__ edge_src,
    const int* __restrict__ edge_dst,
    const float* __restrict__ edge_w,
    float* __restrict__ neigh)
{
    const long long tid = (long long)blockIdx.x * blockDim.x + threadIdx.x;
    const int e = (int)(tid >> 6);
    const int d = (int)(tid & 63);
    if (e >= N_EDGES) return;
    atomicAdd(&neigh[(long long)edge_dst[e] * D + d],
              edge_w[e] * h[(long long)edge_src[e] * D + d]);
}

__global__ __launch_bounds__(256, 2) void linear_f32_kernel(
    const float* __restrict__ h, const float* __restrict__ neigh,
    const float* __restrict__ Ws, const float* __restrict__ bs,
    const float* __restrict__ Wn, const float* __restrict__ bn,
    float* __restrict__ out)
{
    const int lane   = threadIdx.x & 63;
    const int gwave  = (blockIdx.x * blockDim.x + threadIdx.x) >> 6;
    const int nwaves = (gridDim.x * blockDim.x) >> 6;

    float Wsr[D], Wnr[D];
#pragma unroll
    for (int k = 0; k < D; k += 4) {
        const float4 a = *(const float4*)&Ws[(size_t)lane * D + k];
        const float4 b = *(const float4*)&Wn[(size_t)lane * D + k];
        Wsr[k] = a.x; Wsr[k+1] = a.y; Wsr[k+2] = a.z; Wsr[k+3] = a.w;
        Wnr[k] = b.x; Wnr[k+1] = b.y; Wnr[k+2] = b.z; Wnr[k+3] = b.w;
    }
    const float bias = bs[lane] + bn[lane];

    for (int n = gwave; n < N_NODES; n += nwaves) {
        const float hv = h[(size_t)n * D + lane];
        const float nv = neigh[(size_t)n * D + lane];
        float o = bias;
#pragma unroll
        for (int k = 0; k < D; ++k) {
            o = fmaf(lane_bcast(hv, k), Wsr[k], o);
            o = fmaf(lane_bcast(nv, k), Wnr[k], o);
        }
        out[(size_t)n * D + lane] = fmaxf(o, 0.f);
    }
}

extern "C" void kernel_launch(void* const* d_in, const int* in_sizes, int n_in,
                              void* d_out, int out_size, void* d_ws, size_t ws_size,
                              hipStream_t stream)
{
    const float* h        = (const float*)d_in[0];
    const int*   edge_src = (const int*)d_in[1];
    const int*   edge_dst = (const int*)d_in[2];
    const float* edge_w   = (const float*)d_in[3];
    const float* W_self   = (const float*)d_in[4];
    const float* b_self   = (const float*)d_in[5];
    const float* W_neigh  = (const float*)d_in[6];
    const float* b_neigh  = (const float*)d_in[7];
    float*       out      = (float*)d_out;

    // ws layout
    int2*     edges  = (int2*)d_ws;                               // NB*CAP int2
    int2*     offs2  = edges + (size_t)NB * CAP;                  // N_NODES int2
    ushort_t* hb     = (ushort_t*)(offs2 + N_NODES);              // N*D ushort
    int*      cursor = (int*)(hb + (size_t)N_NODES * D);          // NB
    const size_t needed = (size_t)NB * CAP * 8 + (size_t)N_NODES * 8
                        + (size_t)N_NODES * D * 2 + NB * 4;

    if (ws_size >= needed) {
        hipMemsetAsync(cursor, 0, NB * sizeof(int), stream);
        bin_h2b_kernel<<<NCHUNKS * 2, BT, 0, stream>>>(
            edge_src, edge_dst, edge_w, cursor, edges, h, hb);
        bucket_csr_kernel<<<NB, CT, 0, stream>>>(cursor, edges, offs2);
        gather_linear_kernel<<<(N_NODES + GBLK - 1) / GBLK, 256, 0, stream>>>(
            hb, edges, offs2, W_self, b_self, W_neigh, b_neigh, out);
    } else {
        float* neigh_fb = (float*)d_ws;
        hipMemsetAsync(neigh_fb, 0, (size_t)N_NODES * D * sizeof(float), stream);
        const long long total = (long long)N_EDGES * 64;
        sage_scatter<<<(int)((total + 255) / 256), 256, 0, stream>>>(
            h, edge_src, edge_dst, edge_w, neigh_fb);
        linear_f32_kernel<<<1024, 256, 0, stream>>>(h, neigh_fb, W_self, b_self,
                                                    W_neigh, b_neigh, out);
    }
}

// Round 11
// 147.336 us; speedup vs baseline: 1.4829x; 1.1265x over previous
//
#include <hip/hip_runtime.h>

#define N_NODES 50000
#define N_EDGES 800000
#define D 64

#define NPB 200                      // nodes per bucket
#define NB  250                      // buckets (NPB*NB == N_NODES)
#define CAP 4096                     // record capacity per bucket (mean 3200, 15.8 sigma)
#define BT  512                      // threads for bin (8 waves)
#define EPT 4                        // edges per thread in bin
#define CHUNK_E (BT * EPT)           // 2048 edges per block
#define NCHUNKS ((N_EDGES + CHUNK_E - 1) / CHUNK_E)   // 391
#define CT  1024                     // bucket_csr threads (16 waves)
#define GBLK 16                      // nodes per fused gather+linear block (= 1 MFMA tile)

typedef unsigned short ushort_t;
typedef unsigned int   uint_t;
typedef __attribute__((ext_vector_type(8))) short   short8;
typedef __attribute__((ext_vector_type(4))) float   float4v;

// bf16 helpers (RNE down-convert; up-convert is exact)
__device__ __forceinline__ ushort_t f2b(float f) {
    uint_t u = __float_as_uint(f);
    return (ushort_t)((u + 0x7FFFu + ((u >> 16) & 1u)) >> 16);
}
__device__ __forceinline__ float b2f(ushort_t b) {
    return __uint_as_float((uint_t)b << 16);
}
__device__ __forceinline__ float lane_bcast(float v, int l) {
    return __int_as_float(__builtin_amdgcn_readlane(__float_as_int(v), l));
}

// ---------------------------------------------------------------------------
// ws layout (16B-aligned sections):
//   edges  : int2[NB*CAP]     (8.19 MB) bucket-grouped then node-sorted in place
//   offs2  : int2[N_NODES]    (0.4 MB)  per-node (beg,end)
//   h_bf16 : ushort[N*D]      (6.4 MB)
//   cursor : int[NB]          (memset 0; bin rebases to b*CAP + old)
// Binned record: .x=(src<<8)|local_dst, .y=bits(w). Sorted: .x=src, .y=bits(w).
// neigh never touches global: staged in LDS inside the fused kernel.
// ---------------------------------------------------------------------------

// ---------------- K1: bin edges by bucket (blocks < NCHUNKS) + h->bf16 (rest) ----
__global__ __launch_bounds__(BT) void bin_h2b_kernel(
    const int* __restrict__ src, const int* __restrict__ dst,
    const float* __restrict__ w, int* __restrict__ cursor,
    int2* __restrict__ bedges,
    const float* __restrict__ h, ushort_t* __restrict__ hb)
{
    if (blockIdx.x >= NCHUNKS) {
        const int nb = gridDim.x - NCHUNKS;
        for (int i = (blockIdx.x - NCHUNKS) * BT + threadIdx.x;
             i < N_NODES * D / 4; i += nb * BT) {
            const float4 v = ((const float4*)h)[i];
            ushort4 o;
            o.x = f2b(v.x); o.y = f2b(v.y); o.z = f2b(v.z); o.w = f2b(v.w);
            ((ushort4*)hb)[i] = o;
        }
        return;
    }

    __shared__ int lh[NB];
    __shared__ int loff[NB];
    __shared__ int lcur[NB];
    __shared__ int gpos[NB];
    __shared__ int part[256];
    __shared__ int2 stage[CHUNK_E];
    __shared__ unsigned char sbk[CHUNK_E];

    const int t = threadIdx.x;
    for (int i = t; i < NB; i += BT) lh[i] = 0;
    __syncthreads();

    const int base = blockIdx.x * CHUNK_E;
    int   my_b[EPT];
    int   my_p[EPT];
    float my_w[EPT];
#pragma unroll
    for (int k = 0; k < EPT; ++k) {
        const int e = base + k * BT + t;
        if (e < N_EDGES) {
            const int d = dst[e];
            const int b = (unsigned)d / NPB;
            my_b[k] = b;
            my_p[k] = (src[e] << 8) | (d - b * NPB);
            my_w[k] = w[e];
            atomicAdd(&lh[b], 1);
        } else {
            my_b[k] = -1;
        }
    }
    __syncthreads();

    const int v = (t < NB) ? lh[t] : 0;
    if (t < 256) part[t] = v;
    __syncthreads();
    for (int off = 1; off < 256; off <<= 1) {
        int p = 0;
        if (t < 256 && t >= off) p = part[t - off];
        __syncthreads();
        if (t < 256) part[t] += p;
        __syncthreads();
    }
    if (t < NB) { loff[t] = part[t] - v; lcur[t] = part[t] - v; }
    __syncthreads();

#pragma unroll
    for (int k = 0; k < EPT; ++k) {
        if (my_b[k] >= 0) {
            const int p = atomicAdd(&lcur[my_b[k]], 1);
            stage[p] = make_int2(my_p[k], __float_as_int(my_w[k]));
            sbk[p] = (unsigned char)my_b[k];
        }
    }
    __syncthreads();

    if (t < NB && lh[t] > 0)
        gpos[t] = t * CAP + atomicAdd(&cursor[t], lh[t]);
    __syncthreads();

    const int tot = min(N_EDGES - base, CHUNK_E);
    for (int s = t; s < tot; s += BT) {
        const int b = sbk[s];
        bedges[gpos[b] + (s - loff[b])] = stage[s];
    }
}

// ---------------- K2: per-bucket node-exact CSR (in place) ----------------
__global__ __launch_bounds__(CT) void bucket_csr_kernel(
    const int* __restrict__ cursor, int2* __restrict__ edges,
    int2* __restrict__ offs2)
{
    __shared__ int  lcur[NPB];
    __shared__ int  part[256];
    __shared__ int2 stage[CAP];

    const int b   = blockIdx.x;
    const int t   = threadIdx.x;
    const int gb  = b * CAP;
    const int cnt = min(cursor[b], CAP);

    // per-node histogram
    if (t < NPB) lcur[t] = 0;
    __syncthreads();
    for (int e = t; e < cnt; e += CT)
        atomicAdd(&lcur[edges[gb + e].x & 255], 1);
    __syncthreads();

    // exclusive scan of NPB counts (first 256 threads)
    const int v = (t < NPB) ? lcur[t] : 0;
    if (t < 256) part[t] = v;
    __syncthreads();
    for (int off = 1; off < 256; off <<= 1) {
        int p = 0;
        if (t < 256 && t >= off) p = part[t - off];
        __syncthreads();
        if (t < 256) part[t] += p;
        __syncthreads();
    }
    if (t < NPB) {
        const int ex = part[t] - v;
        lcur[t] = ex;
        offs2[b * NPB + t] = make_int2(gb + ex, gb + ex + v);
    }
    __syncthreads();

    // position via LDS atomics, scatter into LDS stage
    for (int e = t; e < cnt; e += CT) {
        const int2 r = edges[gb + e];
        const int p = atomicAdd(&lcur[r.x & 255], 1);
        stage[p] = make_int2(r.x >> 8, r.y);
    }
    __syncthreads();
    // fully coalesced in-place flush
    for (int s = t; s < cnt; s += CT)
        edges[gb + s] = stage[s];
}

// ---------------- K3: fused gather (8 waves x 2 nodes) + MFMA linear ----------
// Block = 512 threads = 8 waves = 16 nodes (one MFMA tile). Phase 1: wave w
// gathers nodes 2w, 2w+1 with the proven 8-deep MLP loop, bf16 rows to LDS.
// Phase 2: waves 0-3 each run one 16-col tile of the 16x16x32 MFMA linear.
// 3125 blocks x 8 waves = 25k waves restores R9-level latency hiding.
__global__ __launch_bounds__(512) void gather_linear_kernel(
    const ushort_t* __restrict__ hb, const int2* __restrict__ edges,
    const int2* __restrict__ offs2,
    const float* __restrict__ Ws, const float* __restrict__ bs,
    const float* __restrict__ Wn, const float* __restrict__ bn,
    float* __restrict__ out)
{
    __shared__ ushort_t nstage[GBLK * D];   // 2 KB

    const int wave  = threadIdx.x >> 6;     // 0..7
    const int lane  = threadIdx.x & 63;
    const int node0 = blockIdx.x * GBLK;

    // ---- phase 1: 2 nodes per wave ----
#pragma unroll
    for (int jj = 0; jj < 2; ++jj) {
        const int j = wave * 2 + jj;        // node-in-block 0..15
        const int node = node0 + j;
        if (node < N_NODES) {
            const int2 be = offs2[node];
            const int beg = be.x, end = be.y;
            float acc = 0.f;
            int e = beg;
            for (; e + 8 <= end; e += 8) {
                int2  r[8];
                float vv[8];
#pragma unroll
                for (int k = 0; k < 8; ++k) r[k] = edges[e + k];
#pragma unroll
                for (int k = 0; k < 8; ++k) vv[k] = b2f(hb[(size_t)r[k].x * D + lane]);
#pragma unroll
                for (int k = 0; k < 8; ++k) acc = fmaf(__int_as_float(r[k].y), vv[k], acc);
            }
            for (; e + 4 <= end; e += 4) {
                const int2 e0 = edges[e], e1 = edges[e + 1], e2 = edges[e + 2], e3 = edges[e + 3];
                const float v0 = b2f(hb[(size_t)e0.x * D + lane]);
                const float v1 = b2f(hb[(size_t)e1.x * D + lane]);
                const float v2 = b2f(hb[(size_t)e2.x * D + lane]);
                const float v3 = b2f(hb[(size_t)e3.x * D + lane]);
                acc = fmaf(__int_as_float(e0.y), v0, acc);
                acc = fmaf(__int_as_float(e1.y), v1, acc);
                acc = fmaf(__int_as_float(e2.y), v2, acc);
                acc = fmaf(__int_as_float(e3.y), v3, acc);
            }
            for (; e < end; ++e) {
                const int2 r = edges[e];
                acc = fmaf(__int_as_float(r.y), b2f(hb[(size_t)r.x * D + lane]), acc);
            }
            nstage[j * D + lane] = f2b(acc);
        }
    }
    __syncthreads();

    // ---- phase 2: waves 0-3, one 16-col tile each ----
    const int nt = wave;
    if (nt >= 4 || node0 >= N_NODES) return;
    const int row16 = lane & 15;
    const int quad  = lane >> 4;

    const size_t abase = (size_t)(node0 + row16) * D + quad * 8;
    const short8 ah0 = *(const short8*)(hb + abase);
    const short8 ah1 = *(const short8*)(hb + abase + 32);
    const ushort_t* sp = nstage + row16 * D + quad * 8;
    const short8 an0 = *(const short8*)sp;
    const short8 an1 = *(const short8*)(sp + 32);

    const int col = nt * 16 + row16;
    const float* wsr = Ws + (size_t)col * D + quad * 8;
    const float* wnr = Wn + (size_t)col * D + quad * 8;
    short8 bw[4];   // ws_k0, ws_k1, wn_k0, wn_k1
#pragma unroll
    for (int f = 0; f < 4; ++f) {
        const float* p = (f < 2 ? wsr : wnr) + (f & 1) * 32;
        const float4 w0 = *(const float4*)p;
        const float4 w1 = *(const float4*)(p + 4);
        short8 bwv;
        bwv[0] = (short)f2b(w0.x); bwv[1] = (short)f2b(w0.y);
        bwv[2] = (short)f2b(w0.z); bwv[3] = (short)f2b(w0.w);
        bwv[4] = (short)f2b(w1.x); bwv[5] = (short)f2b(w1.y);
        bwv[6] = (short)f2b(w1.z); bwv[7] = (short)f2b(w1.w);
        bw[f] = bwv;
    }
    float4v acc = {0.f, 0.f, 0.f, 0.f};
    acc = __builtin_amdgcn_mfma_f32_16x16x32_bf16(ah0, bw[0], acc, 0, 0, 0);
    acc = __builtin_amdgcn_mfma_f32_16x16x32_bf16(ah1, bw[1], acc, 0, 0, 0);
    acc = __builtin_amdgcn_mfma_f32_16x16x32_bf16(an0, bw[2], acc, 0, 0, 0);
    acc = __builtin_amdgcn_mfma_f32_16x16x32_bf16(an1, bw[3], acc, 0, 0, 0);

    const float bias = bs[col] + bn[col];
#pragma unroll
    for (int r = 0; r < 4; ++r) {
        const int m = quad * 4 + r;
        out[(size_t)(node0 + m) * D + col] = fmaxf(acc[r] + bias, 0.f);
    }
}

// ---------------- fallback path (ws too small): fp32 atomic scatter ----------------
__global__ __launch_bounds__(256) void sage_scatter(
    const float* __restrict__ h,
    const int* __restrict__ edge_src,
    const int* __restrict__ edge_dst,
    const float* __restrict__ edge_w,
    float* __restrict__ neigh)
{
    const long long tid = (long long)blockIdx.x * blockDim.x + threadIdx.x;
    const int e = (int)(tid >> 6);
    const int d = (int)(tid & 63);
    if (e >= N_EDGES) return;
    atomicAdd(&neigh[(long long)edge_dst[e] * D + d],
              edge_w[e] * h[(long long)edge_src[e] * D + d]);
}

__global__ __launch_bounds__(256, 2) void linear_f32_kernel(
    const float* __restrict__ h, const float* __restrict__ neigh,
    const float* __restrict__ Ws, const float* __restrict__ bs,
    const float* __restrict__ Wn, const float* __restrict__ bn,
    float* __restrict__ out)
{
    const int lane   = threadIdx.x & 63;
    const int gwave  = (blockIdx.x * blockDim.x + threadIdx.x) >> 6;
    const int nwaves = (gridDim.x * blockDim.x) >> 6;

    float Wsr[D], Wnr[D];
#pragma unroll
    for (int k = 0; k < D; k += 4) {
        const float4 a = *(const float4*)&Ws[(size_t)lane * D + k];
        const float4 b = *(const float4*)&Wn[(size_t)lane * D + k];
        Wsr[k] = a.x; Wsr[k+1] = a.y; Wsr[k+2] = a.z; Wsr[k+3] = a.w;
        Wnr[k] = b.x; Wnr[k+1] = b.y; Wnr[k+2] = b.z; Wnr[k+3] = b.w;
    }
    const float bias = bs[lane] + bn[lane];

    for (int n = gwave; n < N_NODES; n += nwaves) {
        const float hv = h[(size_t)n * D + lane];
        const float nv = neigh[(size_t)n * D + lane];
        float o = bias;
#pragma unroll
        for (int k = 0; k < D; ++k) {
            o = fmaf(lane_bcast(hv, k), Wsr[k], o);
            o = fmaf(lane_bcast(nv, k), Wnr[k], o);
        }
        out[(size_t)n * D + lane] = fmaxf(o, 0.f);
    }
}

extern "C" void kernel_launch(void* const* d_in, const int* in_sizes, int n_in,
                              void* d_out, int out_size, void* d_ws, size_t ws_size,
                              hipStream_t stream)
{
    const float* h        = (const float*)d_in[0];
    const int*   edge_src = (const int*)d_in[1];
    const int*   edge_dst = (const int*)d_in[2];
    const float* edge_w   = (const float*)d_in[3];
    const float* W_self   = (const float*)d_in[4];
    const float* b_self   = (const float*)d_in[5];
    const float* W_neigh  = (const float*)d_in[6];
    const float* b_neigh  = (const float*)d_in[7];
    float*       out      = (float*)d_out;

    // ws layout
    int2*     edges  = (int2*)d_ws;                               // NB*CAP int2
    int2*     offs2  = edges + (size_t)NB * CAP;                  // N_NODES int2
    ushort_t* hb     = (ushort_t*)(offs2 + N_NODES);              // N*D ushort
    int*      cursor = (int*)(hb + (size_t)N_NODES * D);          // NB
    const size_t needed = (size_t)NB * CAP * 8 + (size_t)N_NODES * 8
                        + (size_t)N_NODES * D * 2 + NB * 4;

    if (ws_size >= needed) {
        hipMemsetAsync(cursor, 0, NB * sizeof(int), stream);
        bin_h2b_kernel<<<NCHUNKS * 2, BT, 0, stream>>>(
            edge_src, edge_dst, edge_w, cursor, edges, h, hb);
        bucket_csr_kernel<<<NB, CT, 0, stream>>>(cursor, edges, offs2);
        gather_linear_kernel<<<(N_NODES + GBLK - 1) / GBLK, 512, 0, stream>>>(
            hb, edges, offs2, W_self, b_self, W_neigh, b_neigh, out);
    } else {
        float* neigh_fb = (float*)d_ws;
        hipMemsetAsync(neigh_fb, 0, (size_t)N_NODES * D * sizeof(float), stream);
        const long long total = (long long)N_EDGES * 64;
        sage_scatter<<<(int)((total + 255) / 256), 256, 0, stream>>>(
            h, edge_src, edge_dst, edge_w, neigh_fb);
        linear_f32_kernel<<<1024, 256, 0, stream>>>(h, neigh_fb, W_self, b_self,
                                                    W_neigh, b_neigh, out);
    }
}

// Round 12
// 145.292 us; speedup vs baseline: 1.5037x; 1.0141x over previous
//
#include <hip/hip_runtime.h>

#define N_NODES 50000
#define N_EDGES 800000
#define D 64

#define NPB 200                      // nodes per bucket
#define NB  250                      // buckets (NPB*NB == N_NODES)
#define CAP 4096                     // record capacity per bucket (mean 3200, 15.8 sigma)
#define BT  512                      // threads for bin (8 waves)
#define EPT 4                        // edges per thread in bin
#define CHUNK_E (BT * EPT)           // 2048 edges per block
#define NCHUNKS ((N_EDGES + CHUNK_E - 1) / CHUNK_E)   // 391
#define CT  1024                     // bucket_csr threads (16 waves)
#define GBLK 16                      // nodes per fused gather+linear block (= 1 MFMA tile)

typedef unsigned short ushort_t;
typedef unsigned int   uint_t;
typedef __attribute__((ext_vector_type(8))) short   short8;
typedef __attribute__((ext_vector_type(4))) float   float4v;

// bf16 helpers (RNE down-convert; up-convert is exact)
__device__ __forceinline__ ushort_t f2b(float f) {
    uint_t u = __float_as_uint(f);
    return (ushort_t)((u + 0x7FFFu + ((u >> 16) & 1u)) >> 16);
}
__device__ __forceinline__ float b2f(ushort_t b) {
    return __uint_as_float((uint_t)b << 16);
}
// fp32 bits -> bf16 bits (RNE), kept in the HIGH 16 bits of a uint
__device__ __forceinline__ uint_t rne_hi16(uint_t u) {
    return (u + 0x7FFFu + ((u >> 16) & 1u)) & 0xFFFF0000u;
}
__device__ __forceinline__ float lane_bcast(float v, int l) {
    return __int_as_float(__builtin_amdgcn_readlane(__float_as_int(v), l));
}

// ---------------------------------------------------------------------------
// ws layout (16B-aligned sections):
//   bedges : int2[NB*CAP]     (8.19 MB) bucket-grouped packed records (bin out)
//   pedges : uint[NB*CAP]     (4.10 MB) node-sorted records: src | (w_bf16<<16)
//   offs2  : int2[N_NODES]    (0.4 MB)  per-node (beg,end) into pedges
//   h_bf16 : ushort[N*D]      (6.4 MB)
//   cursor : int[NB]          (memset 0; bin rebases to b*CAP + old)
// Binned record: .x=(src<<8)|local_dst, .y=bits(w).
// neigh never touches global: staged in LDS inside the fused kernel.
// ---------------------------------------------------------------------------

// ---------------- K1: bin edges by bucket (blocks < NCHUNKS) + h->bf16 (rest) ----
__global__ __launch_bounds__(BT) void bin_h2b_kernel(
    const int* __restrict__ src, const int* __restrict__ dst,
    const float* __restrict__ w, int* __restrict__ cursor,
    int2* __restrict__ bedges,
    const float* __restrict__ h, ushort_t* __restrict__ hb)
{
    if (blockIdx.x >= NCHUNKS) {
        const int nb = gridDim.x - NCHUNKS;
        for (int i = (blockIdx.x - NCHUNKS) * BT + threadIdx.x;
             i < N_NODES * D / 4; i += nb * BT) {
            const float4 v = ((const float4*)h)[i];
            ushort4 o;
            o.x = f2b(v.x); o.y = f2b(v.y); o.z = f2b(v.z); o.w = f2b(v.w);
            ((ushort4*)hb)[i] = o;
        }
        return;
    }

    __shared__ int lh[NB];
    __shared__ int loff[NB];
    __shared__ int lcur[NB];
    __shared__ int gpos[NB];
    __shared__ int part[256];
    __shared__ int2 stage[CHUNK_E];
    __shared__ unsigned char sbk[CHUNK_E];

    const int t = threadIdx.x;
    for (int i = t; i < NB; i += BT) lh[i] = 0;
    __syncthreads();

    const int base = blockIdx.x * CHUNK_E;
    int   my_b[EPT];
    int   my_p[EPT];
    float my_w[EPT];
#pragma unroll
    for (int k = 0; k < EPT; ++k) {
        const int e = base + k * BT + t;
        if (e < N_EDGES) {
            const int d = dst[e];
            const int b = (unsigned)d / NPB;
            my_b[k] = b;
            my_p[k] = (src[e] << 8) | (d - b * NPB);
            my_w[k] = w[e];
            atomicAdd(&lh[b], 1);
        } else {
            my_b[k] = -1;
        }
    }
    __syncthreads();

    const int v = (t < NB) ? lh[t] : 0;
    if (t < 256) part[t] = v;
    __syncthreads();
    for (int off = 1; off < 256; off <<= 1) {
        int p = 0;
        if (t < 256 && t >= off) p = part[t - off];
        __syncthreads();
        if (t < 256) part[t] += p;
        __syncthreads();
    }
    if (t < NB) { loff[t] = part[t] - v; lcur[t] = part[t] - v; }
    __syncthreads();

#pragma unroll
    for (int k = 0; k < EPT; ++k) {
        if (my_b[k] >= 0) {
            const int p = atomicAdd(&lcur[my_b[k]], 1);
            stage[p] = make_int2(my_p[k], __float_as_int(my_w[k]));
            sbk[p] = (unsigned char)my_b[k];
        }
    }
    __syncthreads();

    if (t < NB && lh[t] > 0)
        gpos[t] = t * CAP + atomicAdd(&cursor[t], lh[t]);
    __syncthreads();

    const int tot = min(N_EDGES - base, CHUNK_E);
    for (int s = t; s < tot; s += BT) {
        const int b = sbk[s];
        bedges[gpos[b] + (s - loff[b])] = stage[s];
    }
}

// ---------------- K2: per-bucket node-exact CSR -> packed 4-B records ----------
__global__ __launch_bounds__(CT) void bucket_csr_kernel(
    const int* __restrict__ cursor, const int2* __restrict__ bedges,
    uint_t* __restrict__ pedges, int2* __restrict__ offs2)
{
    __shared__ int    lcur[NPB];
    __shared__ int    part[256];
    __shared__ uint_t stage[CAP];   // 16 KB

    const int b   = blockIdx.x;
    const int t   = threadIdx.x;
    const int gb  = b * CAP;
    const int cnt = min(cursor[b], CAP);

    // per-node histogram
    if (t < NPB) lcur[t] = 0;
    __syncthreads();
    for (int e = t; e < cnt; e += CT)
        atomicAdd(&lcur[bedges[gb + e].x & 255], 1);
    __syncthreads();

    // exclusive scan of NPB counts (first 256 threads)
    const int v = (t < NPB) ? lcur[t] : 0;
    if (t < 256) part[t] = v;
    __syncthreads();
    for (int off = 1; off < 256; off <<= 1) {
        int p = 0;
        if (t < 256 && t >= off) p = part[t - off];
        __syncthreads();
        if (t < 256) part[t] += p;
        __syncthreads();
    }
    if (t < NPB) {
        const int ex = part[t] - v;
        lcur[t] = ex;
        offs2[b * NPB + t] = make_int2(gb + ex, gb + ex + v);
    }
    __syncthreads();

    // position via LDS atomics, scatter PACKED into LDS stage
    for (int e = t; e < cnt; e += CT) {
        const int2 r = bedges[gb + e];
        const int p = atomicAdd(&lcur[r.x & 255], 1);
        stage[p] = (uint_t)(r.x >> 8) | rne_hi16((uint_t)r.y);
    }
    __syncthreads();
    // fully coalesced flush to pedges
    for (int s = t; s < cnt; s += CT)
        pedges[gb + s] = stage[s];
}

// ---------------- K3: fused gather (8 waves x 2 nodes, 16-deep) + MFMA linear ----
__global__ __launch_bounds__(512) void gather_linear_kernel(
    const ushort_t* __restrict__ hb, const uint_t* __restrict__ pedges,
    const int2* __restrict__ offs2,
    const float* __restrict__ Ws, const float* __restrict__ bs,
    const float* __restrict__ Wn, const float* __restrict__ bn,
    float* __restrict__ out)
{
    __shared__ ushort_t nstage[GBLK * D];   // 2 KB

    const int wave  = threadIdx.x >> 6;     // 0..7
    const int lane  = threadIdx.x & 63;
    const int node0 = blockIdx.x * GBLK;

    // ---- phase 1: 2 nodes per wave, 16-deep MLP ----
#pragma unroll
    for (int jj = 0; jj < 2; ++jj) {
        const int j = wave * 2 + jj;        // node-in-block 0..15
        const int node = node0 + j;
        if (node < N_NODES) {
            const int2 be = offs2[node];
            const int beg = be.x, end = be.y;
            float acc = 0.f;
            int e = beg;
            for (; e + 16 <= end; e += 16) {
                uint_t r[16];
                float  vv[16];
#pragma unroll
                for (int k = 0; k < 16; ++k) r[k] = pedges[e + k];
#pragma unroll
                for (int k = 0; k < 16; ++k)
                    vv[k] = b2f(hb[(size_t)(r[k] & 0xFFFFu) * D + lane]);
#pragma unroll
                for (int k = 0; k < 16; ++k)
                    acc = fmaf(__uint_as_float(r[k] & 0xFFFF0000u), vv[k], acc);
            }
            for (; e + 4 <= end; e += 4) {
                uint_t r[4];
                float  vv[4];
#pragma unroll
                for (int k = 0; k < 4; ++k) r[k] = pedges[e + k];
#pragma unroll
                for (int k = 0; k < 4; ++k)
                    vv[k] = b2f(hb[(size_t)(r[k] & 0xFFFFu) * D + lane]);
#pragma unroll
                for (int k = 0; k < 4; ++k)
                    acc = fmaf(__uint_as_float(r[k] & 0xFFFF0000u), vv[k], acc);
            }
            for (; e < end; ++e) {
                const uint_t r = pedges[e];
                acc = fmaf(__uint_as_float(r & 0xFFFF0000u),
                           b2f(hb[(size_t)(r & 0xFFFFu) * D + lane]), acc);
            }
            nstage[j * D + lane] = f2b(acc);
        }
    }
    __syncthreads();

    // ---- phase 2: waves 0-3, one 16-col tile each ----
    const int nt = wave;
    if (nt >= 4 || node0 >= N_NODES) return;
    const int row16 = lane & 15;
    const int quad  = lane >> 4;

    const size_t abase = (size_t)(node0 + row16) * D + quad * 8;
    const short8 ah0 = *(const short8*)(hb + abase);
    const short8 ah1 = *(const short8*)(hb + abase + 32);
    const ushort_t* sp = nstage + row16 * D + quad * 8;
    const short8 an0 = *(const short8*)sp;
    const short8 an1 = *(const short8*)(sp + 32);

    const int col = nt * 16 + row16;
    const float* wsr = Ws + (size_t)col * D + quad * 8;
    const float* wnr = Wn + (size_t)col * D + quad * 8;
    short8 bw[4];   // ws_k0, ws_k1, wn_k0, wn_k1
#pragma unroll
    for (int f = 0; f < 4; ++f) {
        const float* p = (f < 2 ? wsr : wnr) + (f & 1) * 32;
        const float4 w0 = *(const float4*)p;
        const float4 w1 = *(const float4*)(p + 4);
        short8 bwv;
        bwv[0] = (short)f2b(w0.x); bwv[1] = (short)f2b(w0.y);
        bwv[2] = (short)f2b(w0.z); bwv[3] = (short)f2b(w0.w);
        bwv[4] = (short)f2b(w1.x); bwv[5] = (short)f2b(w1.y);
        bwv[6] = (short)f2b(w1.z); bwv[7] = (short)f2b(w1.w);
        bw[f] = bwv;
    }
    float4v acc = {0.f, 0.f, 0.f, 0.f};
    acc = __builtin_amdgcn_mfma_f32_16x16x32_bf16(ah0, bw[0], acc, 0, 0, 0);
    acc = __builtin_amdgcn_mfma_f32_16x16x32_bf16(ah1, bw[1], acc, 0, 0, 0);
    acc = __builtin_amdgcn_mfma_f32_16x16x32_bf16(an0, bw[2], acc, 0, 0, 0);
    acc = __builtin_amdgcn_mfma_f32_16x16x32_bf16(an1, bw[3], acc, 0, 0, 0);

    const float bias = bs[col] + bn[col];
#pragma unroll
    for (int r = 0; r < 4; ++r) {
        const int m = quad * 4 + r;
        out[(size_t)(node0 + m) * D + col] = fmaxf(acc[r] + bias, 0.f);
    }
}

// ---------------- fallback path (ws too small): fp32 atomic scatter ----------------
__global__ __launch_bounds__(256) void sage_scatter(
    const float* __restrict__ h,
    const int* __restrict__ edge_src,
    const int* __restrict__ edge_dst,
    const float* __restrict__ edge_w,
    float* __restrict__ neigh)
{
    const long long tid = (long long)blockIdx.x * blockDim.x + threadIdx.x;
    const int e = (int)(tid >> 6);
    const int d = (int)(tid & 63);
    if (e >= N_EDGES) return;
    atomicAdd(&neigh[(long long)edge_dst[e] * D + d],
              edge_w[e] * h[(long long)edge_src[e] * D + d]);
}

__global__ __launch_bounds__(256, 2) void linear_f32_kernel(
    const float* __restrict__ h, const float* __restrict__ neigh,
    const float* __restrict__ Ws, const float* __restrict__ bs,
    const float* __restrict__ Wn, const float* __restrict__ bn,
    float* __restrict__ out)
{
    const int lane   = threadIdx.x & 63;
    const int gwave  = (blockIdx.x * blockDim.x + threadIdx.x) >> 6;
    const int nwaves = (gridDim.x * blockDim.x) >> 6;

    float Wsr[D], Wnr[D];
#pragma unroll
    for (int k = 0; k < D; k += 4) {
        const float4 a = *(const float4*)&Ws[(size_t)lane * D + k];
        const float4 b = *(const float4*)&Wn[(size_t)lane * D + k];
        Wsr[k] = a.x; Wsr[k+1] = a.y; Wsr[k+2] = a.z; Wsr[k+3] = a.w;
        Wnr[k] = b.x; Wnr[k+1] = b.y; Wnr[k+2] = b.z; Wnr[k+3] = b.w;
    }
    const float bias = bs[lane] + bn[lane];

    for (int n = gwave; n < N_NODES; n += nwaves) {
        const float hv = h[(size_t)n * D + lane];
        const float nv = neigh[(size_t)n * D + lane];
        float o = bias;
#pragma unroll
        for (int k = 0; k < D; ++k) {
            o = fmaf(lane_bcast(hv, k), Wsr[k], o);
            o = fmaf(lane_bcast(nv, k), Wnr[k], o);
        }
        out[(size_t)n * D + lane] = fmaxf(o, 0.f);
    }
}

extern "C" void kernel_launch(void* const* d_in, const int* in_sizes, int n_in,
                              void* d_out, int out_size, void* d_ws, size_t ws_size,
                              hipStream_t stream)
{
    const float* h        = (const float*)d_in[0];
    const int*   edge_src = (const int*)d_in[1];
    const int*   edge_dst = (const int*)d_in[2];
    const float* edge_w   = (const float*)d_in[3];
    const float* W_self   = (const float*)d_in[4];
    const float* b_self   = (const float*)d_in[5];
    const float* W_neigh  = (const float*)d_in[6];
    const float* b_neigh  = (const float*)d_in[7];
    float*       out      = (float*)d_out;

    // ws layout
    int2*     bedges = (int2*)d_ws;                               // NB*CAP int2
    uint_t*   pedges = (uint_t*)(bedges + (size_t)NB * CAP);      // NB*CAP uint
    int2*     offs2  = (int2*)(pedges + (size_t)NB * CAP);        // N_NODES int2
    ushort_t* hb     = (ushort_t*)(offs2 + N_NODES);              // N*D ushort
    int*      cursor = (int*)(hb + (size_t)N_NODES * D);          // NB
    const size_t needed = (size_t)NB * CAP * 8 + (size_t)NB * CAP * 4
                        + (size_t)N_NODES * 8 + (size_t)N_NODES * D * 2 + NB * 4;

    if (ws_size >= needed) {
        hipMemsetAsync(cursor, 0, NB * sizeof(int), stream);
        bin_h2b_kernel<<<NCHUNKS * 2, BT, 0, stream>>>(
            edge_src, edge_dst, edge_w, cursor, bedges, h, hb);
        bucket_csr_kernel<<<NB, CT, 0, stream>>>(cursor, bedges, pedges, offs2);
        gather_linear_kernel<<<(N_NODES + GBLK - 1) / GBLK, 512, 0, stream>>>(
            hb, pedges, offs2, W_self, b_self, W_neigh, b_neigh, out);
    } else {
        float* neigh_fb = (float*)d_ws;
        hipMemsetAsync(neigh_fb, 0, (size_t)N_NODES * D * sizeof(float), stream);
        const long long total = (long long)N_EDGES * 64;
        sage_scatter<<<(int)((total + 255) / 256), 256, 0, stream>>>(
            h, edge_src, edge_dst, edge_w, neigh_fb);
        linear_f32_kernel<<<1024, 256, 0, stream>>>(h, neigh_fb, W_self, b_self,
                                                    W_neigh, b_neigh, out);
    }
}